// Round 6
// baseline (115.898 us; speedup 1.0000x reference)
//
#include <hip/hip_runtime.h>
#include <hip/hip_bf16.h>

// GradientLayer: 4->128->128->128->5 tanh MLP; per-sample Jacobian (5x4) and
// Hessians of outputs 0 and 4, combined into 17 outputs.
// Round 6 (from validated round 5 core):
//  - 16 samples per block (16 waves, 1024 threads, 70 KB LDS). Output writer:
//    608 threads, region-major, consecutive thread -> consecutive address;
//    every block now writes only whole 64-B-aligned cache lines
//    (16*mul*4 B per region at offset base*nb*4 + b0*mul*4, b0 = 16*blockIdx).
//    Kills the partial-line RMW amplification (57 MB -> ~5.5 MB writes):
//    in rounds 4/5 each 64-B line was shared by 4 blocks on 4 different
//    (non-coherent-L2) XCDs, forcing per-XCD read-modify-write at HBM.
//  - Core per-wave MFMA pipeline unchanged from validated round 4/5.

namespace {

constexpr int HID = 128;

using bf16x8 = __attribute__((ext_vector_type(8))) short;
using f32x4  = __attribute__((ext_vector_type(4))) float;
typedef unsigned       __attribute__((may_alias)) u32a;
typedef unsigned short __attribute__((may_alias)) u16a;

#define LDS_FENCE() asm volatile("" ::: "memory")

struct OSpec {
    int base, mul, off;
    int a0, a1, a2, m;
    int b0, b1, b2, m2;
    float s1, s2;
};

// comb2[] indices: value (v,k) at v*5+k, v in 0..14, k in 0..4.
// o_k = comb2[k]; J[k][d] = comb2[5+5d+k];
// Hn[p] = comb2[25+5p]; HFi[p] = comb2[29+5p]; comb2[80]=0, comb2[81]=1.
__constant__ OSpec g_ospec[38] = {
    {0,1,0,   0,80,80,81, 80,80,80,81, 1.f,0.f},   // n
    {1,1,0,   5,80,80,81, 80,80,80,81, 1.f,0.f},   // n_t
    {2,3,0,  10,80,80,81, 80,80,80,81, 1.f,0.f},   // n_grd
    {2,3,1,  15,80,80,81, 80,80,80,81, 1.f,0.f},
    {2,3,2,  20,80,80,81, 80,80,80,81, 1.f,0.f},
    {5,3,0,   1,80,80, 0, 80,80,80,81, 1.f,0.f},   // j = n*v
    {5,3,1,   2,80,80, 0, 80,80,80,81, 1.f,0.f},
    {5,3,2,   3,80,80, 0, 80,80,80,81, 1.f,0.f},
    {8,3,0,  10,15,20, 1, 11,16,21, 0, 1.f,1.f},   // j_div
    {8,3,1,  10,15,20, 2, 12,17,22, 0, 1.f,1.f},
    {8,3,2,  10,15,20, 3, 13,18,23, 0, 1.f,1.f},
    {11,1,0,  4,80,80,81, 80,80,80,81, 1.f,0.f},   // Fi
    {12,3,0, 14,80,80,81, 80,80,80,81, 1.f,0.f},   // Fi_grd
    {12,3,1, 19,80,80,81, 80,80,80,81, 1.f,0.f},
    {12,3,2, 24,80,80,81, 80,80,80,81, 1.f,0.f},
    {15,4,0, 34,39,44,81, 80,80,80,81, 1.f,0.f},   // Fi_lap (HFi p=1,2,3)
    {15,4,1, 49,54,59,81, 80,80,80,81, 1.f,0.f},   //        (p=4,5,6)
    {15,4,2, 54,64,69,81, 80,80,80,81, 1.f,0.f},   //        (p=5,7,8)
    {15,4,3, 59,69,74,81, 80,80,80,81, 1.f,0.f},   //        (p=6,8,9)
    {19,3,0,  1,80,80,81, 80,80,80,81, 1.f,0.f},   // v
    {19,3,1,  2,80,80,81, 80,80,80,81, 1.f,0.f},
    {19,3,2,  3,80,80,81, 80,80,80,81, 1.f,0.f},
    {22,1,0,  5,80,80,81, 80,80,80,81, 1.f,0.f},   // v_t
    {23,3,0,  1,80,80,10, 80,80,80,81, 1.f,0.f},   // v_adv
    {23,3,1,  2,80,80,15, 80,80,80,81, 1.f,0.f},
    {23,3,2,  3,80,80,20, 80,80,80,81, 1.f,0.f},
    {26,1,0, 30,50,65,81, 80,80,80,81, 1.f,0.f},   // v_lap (Hn p=1,5,8)
    {27,3,0, 45,50,55,81, 80,80,80,81, 1.f,0.f},   // v_div_grd (p=4,5,6)
    {27,3,1, 50,60,65,81, 80,80,80,81, 1.f,0.f},   //           (p=5,7,8)
    {27,3,2, 55,65,70,81, 80,80,80,81, 1.f,0.f},   //           (p=6,8,9)
    {30,1,0,  0,80,80,81, 80,80,80,81, 2.f,0.f},   // ro = 2n
    {31,1,0,  5,80,80,81, 80,80,80,81, 2.f,0.f},   // ro_t
    {32,3,0, 10,80,80,81, 80,80,80,81, 2.f,0.f},   // ro_grd
    {32,3,1, 15,80,80,81, 80,80,80,81, 2.f,0.f},
    {32,3,2, 20,80,80,81, 80,80,80,81, 2.f,0.f},
    {35,3,0, 10,15,20, 1, 11,16,21, 0, 2.f,2.f},   // rov_div
    {35,3,1, 10,15,20, 2, 12,17,22, 0, 2.f,2.f},
    {35,3,2, 10,15,20, 3, 13,18,23, 0, 2.f,2.f},
};

// 17 output regions, in memory order. Per block (16 samples) each region
// receives exactly 16*mul consecutive floats starting at base*nb + b0*mul.
__constant__ short g_rstart[18] = {0,16,32,80,128,176,192,240,304,352,368,416,432,480,496,512,560,608};
__constant__ signed char g_roi0[17] = {0,1,2,5,8,11,12,15,19,22,23,26,27,30,31,32,35};
__constant__ signed char g_rmul[17] = {1,1,3,3,3,1,3,4,3,1,3,1,3,1,1,3,3};
__constant__ signed char g_rbase[17]= {0,1,2,5,8,11,12,15,19,22,23,26,27,30,31,32,35};

__device__ __forceinline__ unsigned short f2bf(float f) {
    union { float f; unsigned u; } v; v.f = f;
    unsigned r = v.u + 0x7FFFu + ((v.u >> 16) & 1u);   // RNE
    return (unsigned short)(r >> 16);
}
__device__ __forceinline__ unsigned pk_bf16(float lo, float hi) {
    __hip_bfloat162 h2 = __float22bfloat162_rn(make_float2(lo, hi));
    unsigned r; __builtin_memcpy(&r, &h2, 4); return r;   // lo in bits 0-15
}
__device__ __forceinline__ float tanh_fast(float z) {
    float e = __builtin_amdgcn_exp2f(z * 2.8853900817779268f);
    return 1.0f - 2.0f * __builtin_amdgcn_rcpf(e + 1.0f);
}
// swizzled byte offset inside the per-wave [16][128] bf16 A-buffer
__device__ __forceinline__ int swz(int row, int byte_in_row) {
    return (row * 256 + byte_in_row) ^ ((row & 7) << 4);
}

// ---- pack W1/W2 (+ W3 padded to 16 cols) into B-fragment bf16 in d_ws ------
__global__ void pack_w_kernel(const float* __restrict__ W1,
                              const float* __restrict__ W2,
                              const float* __restrict__ W3,
                              unsigned short* __restrict__ wsB) {
    int t = blockIdx.x * 256 + threadIdx.x;        // 0..34815
    if (t < 32768) {
        int reg  = t & 7;
        int lane = (t >> 3) & 63;
        int nt   = (t >> 9) & 7;
        int kt   = (t >> 12) & 3;
        int layer = (t >> 14) & 1;
        int k = kt * 32 + (lane >> 4) * 8 + reg;
        int n = nt * 16 + (lane & 15);
        const float* W = layer ? W2 : W1;
        wsB[t] = f2bf(W[k * HID + n]);
    } else if (t < 34816) {
        int tt = t - 32768;
        int reg  = tt & 7;
        int lane = (tt >> 3) & 63;
        int kt   = (tt >> 9) & 3;
        int k = kt * 32 + (lane >> 4) * 8 + reg;
        int n = lane & 15;
        wsB[t] = (n < 5) ? f2bf(W3[k * 5 + n]) : (unsigned short)0;
    }
}

__global__ __launch_bounds__(1024, 8) void mlp_pde_kernel(
    const float* __restrict__ x,
    const float* __restrict__ W0, const float* __restrict__ b0,
    const float* __restrict__ b1, const float* __restrict__ b2,
    const float* __restrict__ b3,
    const unsigned short* __restrict__ wsB,
    float* __restrict__ out, int nb)
{
    constexpr int PD[10] = {0,0,0,0,1,1,1,2,2,3};
    constexpr int PE[10] = {0,1,2,3,1,2,3,2,3,3};

    __shared__ float lds[16][1120];                // 4480 B per wave, 71680 B/block
    const int wave = threadIdx.x >> 6;
    const int lane = threadIdx.x & 63;
    char* abuf = (char*)lds[wave];                 // first 4096 B: [16][128] bf16 (swizzled)
    const int b0s = blockIdx.x * 16;
    int b = b0s + wave;
    if (b >= nb) b = nb - 1;

    // ---------------- layer 0 (4 -> 128), fp32, lane owns cols 2l,2l+1 ------
    {
        const int j0 = lane * 2;
        const float4 xv = *reinterpret_cast<const float4*>(x + 4 * b);
        float w0d[4][2];
        #pragma unroll
        for (int d = 0; d < 4; ++d) {
            float2 w = *reinterpret_cast<const float2*>(W0 + d * HID + j0);
            w0d[d][0] = w.x; w0d[d][1] = w.y;
        }
        const float2 bb0 = *reinterpret_cast<const float2*>(b0 + j0);
        float val[15][2];
        #pragma unroll
        for (int jj = 0; jj < 2; ++jj) {
            float z = ((jj == 0) ? bb0.x : bb0.y)
                    + xv.x * w0d[0][jj] + xv.y * w0d[1][jj]
                    + xv.z * w0d[2][jj] + xv.w * w0d[3][jj];
            float h = tanh_fast(z);
            float s = 1.f - h * h;
            val[0][jj] = h;
            #pragma unroll
            for (int d = 0; d < 4; ++d) val[1 + d][jj] = s * w0d[d][jj];
            #pragma unroll
            for (int p = 0; p < 10; ++p)
                val[5 + p][jj] = -2.f * h * s * w0d[PD[p]][jj] * w0d[PE[p]][jj];
        }
        #pragma unroll
        for (int v = 0; v < 15; ++v)
            *reinterpret_cast<u32a*>(abuf + swz(v, j0 * 2)) = pk_bf16(val[v][0], val[v][1]);
        *reinterpret_cast<u32a*>(abuf + swz(15, j0 * 2)) = 0u;  // pad row
    }
    LDS_FENCE();   // layer-0 stores -> afrag reads

    // ---------------- layers 1,2 via MFMA -----------------------------------
    const int jloc = lane & 15;                    // column within 16-wide tile
    const int rgrp = lane >> 4;                    // row group: rows 4r..4r+3
    #pragma unroll 1
    for (int layer = 0; layer < 2; ++layer) {
        // A fragments: lane holds A[m = lane&15][k = kt*32 + (lane>>4)*8 + 0..7]
        bf16x8 afrag[4];
        #pragma unroll
        for (int kt = 0; kt < 4; ++kt)
            afrag[kt] = *reinterpret_cast<const bf16x8*>(
                abuf + (swz(jloc, kt * 64 + rgrp * 16)));
        LDS_FENCE();   // afrag reads -> recombination stores (WAR)
        const float* bias = layer ? b2 : b1;
        float bv[8];
        #pragma unroll
        for (int nt = 0; nt < 8; ++nt) bv[nt] = bias[nt * 16 + jloc];

        #pragma unroll 1
        for (int nt = 0; nt < 8; ++nt) {
            f32x4 acc = {0.f, 0.f, 0.f, 0.f};
            #pragma unroll
            for (int kt = 0; kt < 4; ++kt) {
                bf16x8 bfrag = *reinterpret_cast<const bf16x8*>(
                    wsB + ((size_t)((layer * 4 + kt) * 8 + nt) * 512 + lane * 8));
                acc = __builtin_amdgcn_mfma_f32_16x16x32_bf16(afrag[kt], bfrag, acc, 0, 0, 0);
            }
            // broadcast primal + first-order tangents within the column group
            float z0 = __shfl(acc[0], jloc, 64);         // row 0 (primal z)
            float u0 = __shfl(acc[1], jloc, 64);         // row 1 (dz_0)
            float u1 = __shfl(acc[2], jloc, 64);         // row 2 (dz_1)
            float u2 = __shfl(acc[3], jloc, 64);         // row 3 (dz_2)
            float u3 = __shfl(acc[0], jloc + 16, 64);    // row 4 (dz_3)
            float h = tanh_fast(z0 + bv[nt]);
            float s = 1.f - h * h;
            float c = -2.f * h * s;
            float nv[4];
            if (rgrp == 0) {
                nv[0] = h;           nv[1] = s * u0;
                nv[2] = s * u1;      nv[3] = s * u2;
            } else if (rgrp == 1) {
                nv[0] = s * u3;
                nv[1] = fmaf(c * u0, u0, s * acc[1]);    // row 5  (0,0)
                nv[2] = fmaf(c * u0, u1, s * acc[2]);    // row 6  (0,1)
                nv[3] = fmaf(c * u0, u2, s * acc[3]);    // row 7  (0,2)
            } else if (rgrp == 2) {
                nv[0] = fmaf(c * u0, u3, s * acc[0]);    // row 8  (0,3)
                nv[1] = fmaf(c * u1, u1, s * acc[1]);    // row 9  (1,1)
                nv[2] = fmaf(c * u1, u2, s * acc[2]);    // row 10 (1,2)
                nv[3] = fmaf(c * u1, u3, s * acc[3]);    // row 11 (1,3)
            } else {
                nv[0] = fmaf(c * u2, u2, s * acc[0]);    // row 12 (2,2)
                nv[1] = fmaf(c * u2, u3, s * acc[1]);    // row 13 (2,3)
                nv[2] = fmaf(c * u3, u3, s * acc[2]);    // row 14 (3,3)
                nv[3] = 0.f;                             // pad row 15
            }
            unsigned pk01 = pk_bf16(nv[0], nv[1]);
            unsigned pk23 = pk_bf16(nv[2], nv[3]);
            const int bcol = (nt * 16 + jloc) * 2;
            *reinterpret_cast<u16a*>(abuf + swz(rgrp * 4 + 0, bcol)) = (unsigned short)pk01;
            *reinterpret_cast<u16a*>(abuf + swz(rgrp * 4 + 1, bcol)) = (unsigned short)(pk01 >> 16);
            *reinterpret_cast<u16a*>(abuf + swz(rgrp * 4 + 2, bcol)) = (unsigned short)pk23;
            *reinterpret_cast<u16a*>(abuf + swz(rgrp * 4 + 3, bcol)) = (unsigned short)(pk23 >> 16);
        }
        LDS_FENCE();   // recombination stores -> next-layer / epilogue reads
    }

    // ---------------- epilogue: T(16x128) @ W3pad(128x16) via MFMA ----------
    bf16x8 tfrag[4];
    #pragma unroll
    for (int kt = 0; kt < 4; ++kt)
        tfrag[kt] = *reinterpret_cast<const bf16x8*>(
            abuf + (swz(jloc, kt * 64 + rgrp * 16)));
    LDS_FENCE();

    f32x4 facc = {0.f, 0.f, 0.f, 0.f};
    #pragma unroll
    for (int kt = 0; kt < 4; ++kt) {
        bf16x8 w3f = *reinterpret_cast<const bf16x8*>(
            wsB + 32768 + (size_t)(kt * 64 + lane) * 8);
        facc = __builtin_amdgcn_mfma_f32_16x16x32_bf16(tfrag[kt], w3f, facc, 0, 0, 0);
    }

    float* comb2 = lds[wave] + 1024;               // 82 slots
    if (jloc < 5) {
        #pragma unroll
        for (int q = 0; q < 4; ++q) {
            int row = rgrp * 4 + q;                // = vector index v
            float t = facc[q];
            if (row == 0) t += b3[jloc];
            comb2[row * 5 + jloc] = t;             // rows 0..15 -> slots 0..79
        }
    }
    if (lane == 63) { comb2[80] = 0.f; comb2[81] = 1.f; }
    __syncthreads();   // all 16 waves' comb2 visible block-wide

    // ---------------- block-wide whole-line output writer -------------------
    // thread t in [0,608): region-major; consecutive t -> consecutive floats.
    const int t = threadIdx.x;
    if (t < 608) {
        int r = 0;
        #pragma unroll
        for (int i = 1; i < 17; ++i) r += (t >= (int)g_rstart[i]);
        const int idx = t - g_rstart[r];
        const int mul = g_rmul[r];
        const int s   = idx / mul;                 // sample-local 0..15
        const int off = idx - s * mul;
        const OSpec sp = g_ospec[g_roi0[r] + off];
        const float* c2 = lds[s] + 1024;
        float t1 = (c2[sp.a0] + c2[sp.a1] + c2[sp.a2]) * c2[sp.m] * sp.s1;
        float t2 = (c2[sp.b0] + c2[sp.b1] + c2[sp.b2]) * c2[sp.m2] * sp.s2;
        const int bs = b0s + s;
        if (bs < nb)
            out[(int)g_rbase[r] * nb + b0s * mul + idx] = t1 + t2;
    }
}

} // namespace

extern "C" void kernel_launch(void* const* d_in, const int* in_sizes, int n_in,
                              void* d_out, int out_size, void* d_ws, size_t ws_size,
                              hipStream_t stream) {
    const float* x  = (const float*)d_in[0];
    const float* W0 = (const float*)d_in[1];
    const float* b0 = (const float*)d_in[2];
    const float* W1 = (const float*)d_in[3];
    const float* b1 = (const float*)d_in[4];
    const float* W2 = (const float*)d_in[5];
    const float* b2 = (const float*)d_in[6];
    const float* W3 = (const float*)d_in[7];
    const float* b3 = (const float*)d_in[8];
    float* out = (float*)d_out;
    unsigned short* wsB = (unsigned short*)d_ws;   // ~68 KB used

    const int nb = in_sizes[0] / 4;                // 32768
    pack_w_kernel<<<136, 256, 0, stream>>>(W1, W2, W3, wsB);
    const int blocks = (nb + 15) / 16;             // 16 samples (waves) per block
    mlp_pde_kernel<<<blocks, 1024, 0, stream>>>(x, W0, b0, b1, b2, b3, wsB, out, nb);
}

// Round 7
// 88.725 us; speedup vs baseline: 1.3063x; 1.3063x over previous
//
#include <hip/hip_runtime.h>
#include <hip/hip_bf16.h>

// GradientLayer: 4->128->128->128->5 tanh MLP; per-sample Jacobian (5x4) and
// Hessians of outputs 0 and 4, combined into 17 outputs.
// Round 7 (from validated round-4 core):
//  - TWO samples per wave: dual A-fragments/accumulators share every bfrag
//    load (halves per-sample L2 weight streaming, doubles MFMA-chain ILP).
//  - __launch_bounds__(256,4): VGPR cap 128 (was 64 -> compiler squeezed to
//    32 regs, no room to pipeline the 4 bfrag loads + dual chains).
//  - Writer: simple per-wave scattered (rounds 4-6 proved write traffic is
//    not on the critical path; HBM ~6% of peak throughout).

namespace {

constexpr int HID = 128;

using bf16x8 = __attribute__((ext_vector_type(8))) short;
using f32x4  = __attribute__((ext_vector_type(4))) float;
typedef unsigned       __attribute__((may_alias)) u32a;
typedef unsigned short __attribute__((may_alias)) u16a;

#define LDS_FENCE() asm volatile("" ::: "memory")

struct OSpec {
    int base, mul, off;
    int a0, a1, a2, m;
    int b0, b1, b2, m2;
    float s1, s2;
};

// comb2[] indices: value (v,k) at v*5+k, v in 0..14, k in 0..4.
// o_k = comb2[k]; J[k][d] = comb2[5+5d+k];
// Hn[p] = comb2[25+5p]; HFi[p] = comb2[29+5p]; comb2[80]=0, comb2[81]=1.
__constant__ OSpec g_ospec[38] = {
    {0,1,0,   0,80,80,81, 80,80,80,81, 1.f,0.f},   // n
    {1,1,0,   5,80,80,81, 80,80,80,81, 1.f,0.f},   // n_t
    {2,3,0,  10,80,80,81, 80,80,80,81, 1.f,0.f},   // n_grd
    {2,3,1,  15,80,80,81, 80,80,80,81, 1.f,0.f},
    {2,3,2,  20,80,80,81, 80,80,80,81, 1.f,0.f},
    {5,3,0,   1,80,80, 0, 80,80,80,81, 1.f,0.f},   // j = n*v
    {5,3,1,   2,80,80, 0, 80,80,80,81, 1.f,0.f},
    {5,3,2,   3,80,80, 0, 80,80,80,81, 1.f,0.f},
    {8,3,0,  10,15,20, 1, 11,16,21, 0, 1.f,1.f},   // j_div
    {8,3,1,  10,15,20, 2, 12,17,22, 0, 1.f,1.f},
    {8,3,2,  10,15,20, 3, 13,18,23, 0, 1.f,1.f},
    {11,1,0,  4,80,80,81, 80,80,80,81, 1.f,0.f},   // Fi
    {12,3,0, 14,80,80,81, 80,80,80,81, 1.f,0.f},   // Fi_grd
    {12,3,1, 19,80,80,81, 80,80,80,81, 1.f,0.f},
    {12,3,2, 24,80,80,81, 80,80,80,81, 1.f,0.f},
    {15,4,0, 34,39,44,81, 80,80,80,81, 1.f,0.f},   // Fi_lap (HFi p=1,2,3)
    {15,4,1, 49,54,59,81, 80,80,80,81, 1.f,0.f},   //        (p=4,5,6)
    {15,4,2, 54,64,69,81, 80,80,80,81, 1.f,0.f},   //        (p=5,7,8)
    {15,4,3, 59,69,74,81, 80,80,80,81, 1.f,0.f},   //        (p=6,8,9)
    {19,3,0,  1,80,80,81, 80,80,80,81, 1.f,0.f},   // v
    {19,3,1,  2,80,80,81, 80,80,80,81, 1.f,0.f},
    {19,3,2,  3,80,80,81, 80,80,80,81, 1.f,0.f},
    {22,1,0,  5,80,80,81, 80,80,80,81, 1.f,0.f},   // v_t
    {23,3,0,  1,80,80,10, 80,80,80,81, 1.f,0.f},   // v_adv
    {23,3,1,  2,80,80,15, 80,80,80,81, 1.f,0.f},
    {23,3,2,  3,80,80,20, 80,80,80,81, 1.f,0.f},
    {26,1,0, 30,50,65,81, 80,80,80,81, 1.f,0.f},   // v_lap (Hn p=1,5,8)
    {27,3,0, 45,50,55,81, 80,80,80,81, 1.f,0.f},   // v_div_grd (p=4,5,6)
    {27,3,1, 50,60,65,81, 80,80,80,81, 1.f,0.f},   //           (p=5,7,8)
    {27,3,2, 55,65,70,81, 80,80,80,81, 1.f,0.f},   //           (p=6,8,9)
    {30,1,0,  0,80,80,81, 80,80,80,81, 2.f,0.f},   // ro = 2n
    {31,1,0,  5,80,80,81, 80,80,80,81, 2.f,0.f},   // ro_t
    {32,3,0, 10,80,80,81, 80,80,80,81, 2.f,0.f},   // ro_grd
    {32,3,1, 15,80,80,81, 80,80,80,81, 2.f,0.f},
    {32,3,2, 20,80,80,81, 80,80,80,81, 2.f,0.f},
    {35,3,0, 10,15,20, 1, 11,16,21, 0, 2.f,2.f},   // rov_div
    {35,3,1, 10,15,20, 2, 12,17,22, 0, 2.f,2.f},
    {35,3,2, 10,15,20, 3, 13,18,23, 0, 2.f,2.f},
};

__device__ __forceinline__ unsigned short f2bf(float f) {
    union { float f; unsigned u; } v; v.f = f;
    unsigned r = v.u + 0x7FFFu + ((v.u >> 16) & 1u);   // RNE
    return (unsigned short)(r >> 16);
}
__device__ __forceinline__ unsigned pk_bf16(float lo, float hi) {
    __hip_bfloat162 h2 = __float22bfloat162_rn(make_float2(lo, hi));
    unsigned r; __builtin_memcpy(&r, &h2, 4); return r;   // lo in bits 0-15
}
__device__ __forceinline__ float tanh_fast(float z) {
    float e = __builtin_amdgcn_exp2f(z * 2.8853900817779268f);
    return 1.0f - 2.0f * __builtin_amdgcn_rcpf(e + 1.0f);
}
// swizzled byte offset inside a per-sample [16][128] bf16 A-buffer
__device__ __forceinline__ int swz(int row, int byte_in_row) {
    return (row * 256 + byte_in_row) ^ ((row & 7) << 4);
}

// ---- pack W1/W2 (+ W3 padded to 16 cols) into B-fragment bf16 in d_ws ------
__global__ void pack_w_kernel(const float* __restrict__ W1,
                              const float* __restrict__ W2,
                              const float* __restrict__ W3,
                              unsigned short* __restrict__ wsB) {
    int t = blockIdx.x * 256 + threadIdx.x;        // 0..34815
    if (t < 32768) {
        int reg  = t & 7;
        int lane = (t >> 3) & 63;
        int nt   = (t >> 9) & 7;
        int kt   = (t >> 12) & 3;
        int layer = (t >> 14) & 1;
        int k = kt * 32 + (lane >> 4) * 8 + reg;
        int n = nt * 16 + (lane & 15);
        const float* W = layer ? W2 : W1;
        wsB[t] = f2bf(W[k * HID + n]);
    } else if (t < 34816) {
        int tt = t - 32768;
        int reg  = tt & 7;
        int lane = (tt >> 3) & 63;
        int kt   = (tt >> 9) & 3;
        int k = kt * 32 + (lane >> 4) * 8 + reg;
        int n = lane & 15;
        wsB[t] = (n < 5) ? f2bf(W3[k * 5 + n]) : (unsigned short)0;
    }
}

__global__ __launch_bounds__(256, 4) void mlp_pde_kernel(
    const float* __restrict__ x,
    const float* __restrict__ W0, const float* __restrict__ b0,
    const float* __restrict__ b1, const float* __restrict__ b2,
    const float* __restrict__ b3,
    const unsigned short* __restrict__ wsB,
    float* __restrict__ out, int nb)
{
    constexpr int PD[10] = {0,0,0,0,1,1,1,2,2,3};
    constexpr int PE[10] = {0,1,2,3,1,2,3,2,3,3};

    __shared__ float lds[4][2304];                 // 9216 B per wave, 36864 B/block
    const int wave = threadIdx.x >> 6;
    const int lane = threadIdx.x & 63;
    float* wbase = lds[wave];
    char* abufA = (char*)wbase;                    // [16][128] bf16, swizzled
    char* abufB = (char*)wbase + 4096;
    float* combA = wbase + 2048;                   // 82 slots
    float* combB = wbase + 2176;                   // 82 slots
    int bA = blockIdx.x * 8 + wave * 2;
    int bB = bA + 1;
    if (bA >= nb) bA = nb - 1;
    if (bB >= nb) bB = nb - 1;

    // ---------------- layer 0 (4 -> 128), fp32, lane owns cols 2l,2l+1 ------
    {
        const int j0 = lane * 2;
        float w0d[4][2];
        #pragma unroll
        for (int d = 0; d < 4; ++d) {
            float2 w = *reinterpret_cast<const float2*>(W0 + d * HID + j0);
            w0d[d][0] = w.x; w0d[d][1] = w.y;
        }
        const float2 bb0 = *reinterpret_cast<const float2*>(b0 + j0);
        const float4 xvA = *reinterpret_cast<const float4*>(x + 4 * bA);
        const float4 xvB = *reinterpret_cast<const float4*>(x + 4 * bB);
        #pragma unroll
        for (int s = 0; s < 2; ++s) {
            const float4 xv = s ? xvB : xvA;
            char* abuf = s ? abufB : abufA;
            float val[15][2];
            #pragma unroll
            for (int jj = 0; jj < 2; ++jj) {
                float z = ((jj == 0) ? bb0.x : bb0.y)
                        + xv.x * w0d[0][jj] + xv.y * w0d[1][jj]
                        + xv.z * w0d[2][jj] + xv.w * w0d[3][jj];
                float h = tanh_fast(z);
                float sd = 1.f - h * h;
                val[0][jj] = h;
                #pragma unroll
                for (int d = 0; d < 4; ++d) val[1 + d][jj] = sd * w0d[d][jj];
                #pragma unroll
                for (int p = 0; p < 10; ++p)
                    val[5 + p][jj] = -2.f * h * sd * w0d[PD[p]][jj] * w0d[PE[p]][jj];
            }
            #pragma unroll
            for (int v = 0; v < 15; ++v)
                *reinterpret_cast<u32a*>(abuf + swz(v, j0 * 2)) = pk_bf16(val[v][0], val[v][1]);
            *reinterpret_cast<u32a*>(abuf + swz(15, j0 * 2)) = 0u;  // pad row
        }
    }
    LDS_FENCE();   // layer-0 stores -> afrag reads

    // ---------------- layers 1,2 via MFMA (dual sample) ---------------------
    const int jloc = lane & 15;                    // column within 16-wide tile
    const int rgrp = lane >> 4;                    // row group: rows 4r..4r+3

    // chain-rule recombination on the C/D layout; writes new A-tile rows
    auto recomb = [&](const f32x4& acc, char* abuf, float bnt, int nt) {
        float z0 = __shfl(acc[0], jloc, 64);       // row 0 (primal z)
        float u0 = __shfl(acc[1], jloc, 64);       // row 1 (dz_0)
        float u1 = __shfl(acc[2], jloc, 64);       // row 2 (dz_1)
        float u2 = __shfl(acc[3], jloc, 64);       // row 3 (dz_2)
        float u3 = __shfl(acc[0], jloc + 16, 64);  // row 4 (dz_3)
        float h = tanh_fast(z0 + bnt);
        float s = 1.f - h * h;
        float c = -2.f * h * s;
        float nv[4];
        if (rgrp == 0) {
            nv[0] = h;           nv[1] = s * u0;
            nv[2] = s * u1;      nv[3] = s * u2;
        } else if (rgrp == 1) {
            nv[0] = s * u3;
            nv[1] = fmaf(c * u0, u0, s * acc[1]);  // row 5  (0,0)
            nv[2] = fmaf(c * u0, u1, s * acc[2]);  // row 6  (0,1)
            nv[3] = fmaf(c * u0, u2, s * acc[3]);  // row 7  (0,2)
        } else if (rgrp == 2) {
            nv[0] = fmaf(c * u0, u3, s * acc[0]);  // row 8  (0,3)
            nv[1] = fmaf(c * u1, u1, s * acc[1]);  // row 9  (1,1)
            nv[2] = fmaf(c * u1, u2, s * acc[2]);  // row 10 (1,2)
            nv[3] = fmaf(c * u1, u3, s * acc[3]);  // row 11 (1,3)
        } else {
            nv[0] = fmaf(c * u2, u2, s * acc[0]);  // row 12 (2,2)
            nv[1] = fmaf(c * u2, u3, s * acc[1]);  // row 13 (2,3)
            nv[2] = fmaf(c * u3, u3, s * acc[2]);  // row 14 (3,3)
            nv[3] = 0.f;                           // pad row 15
        }
        unsigned pk01 = pk_bf16(nv[0], nv[1]);
        unsigned pk23 = pk_bf16(nv[2], nv[3]);
        const int bcol = (nt * 16 + jloc) * 2;
        *reinterpret_cast<u16a*>(abuf + swz(rgrp * 4 + 0, bcol)) = (unsigned short)pk01;
        *reinterpret_cast<u16a*>(abuf + swz(rgrp * 4 + 1, bcol)) = (unsigned short)(pk01 >> 16);
        *reinterpret_cast<u16a*>(abuf + swz(rgrp * 4 + 2, bcol)) = (unsigned short)pk23;
        *reinterpret_cast<u16a*>(abuf + swz(rgrp * 4 + 3, bcol)) = (unsigned short)(pk23 >> 16);
    };

    #pragma unroll 1
    for (int layer = 0; layer < 2; ++layer) {
        // A fragments: lane holds A[m = lane&15][k = kt*32 + (lane>>4)*8 + 0..7]
        bf16x8 a0[4], a1[4];
        #pragma unroll
        for (int kt = 0; kt < 4; ++kt) {
            a0[kt] = *reinterpret_cast<const bf16x8*>(abufA + swz(jloc, kt * 64 + rgrp * 16));
            a1[kt] = *reinterpret_cast<const bf16x8*>(abufB + swz(jloc, kt * 64 + rgrp * 16));
        }
        LDS_FENCE();   // afrag reads -> recombination stores (WAR)
        const float* bias = layer ? b2 : b1;
        float bv[8];
        #pragma unroll
        for (int nt = 0; nt < 8; ++nt) bv[nt] = bias[nt * 16 + jloc];

        #pragma unroll 1
        for (int nt = 0; nt < 8; ++nt) {
            f32x4 acc0 = {0.f, 0.f, 0.f, 0.f};
            f32x4 acc1 = {0.f, 0.f, 0.f, 0.f};
            #pragma unroll
            for (int kt = 0; kt < 4; ++kt) {
                bf16x8 bfrag = *reinterpret_cast<const bf16x8*>(
                    wsB + ((size_t)((layer * 4 + kt) * 8 + nt) * 512 + lane * 8));
                acc0 = __builtin_amdgcn_mfma_f32_16x16x32_bf16(a0[kt], bfrag, acc0, 0, 0, 0);
                acc1 = __builtin_amdgcn_mfma_f32_16x16x32_bf16(a1[kt], bfrag, acc1, 0, 0, 0);
            }
            recomb(acc0, abufA, bv[nt], nt);
            recomb(acc1, abufB, bv[nt], nt);
        }
        LDS_FENCE();   // recombination stores -> next-layer / epilogue reads
    }

    // ---------------- epilogue: T(16x128) @ W3pad(128x16) via MFMA ----------
    bf16x8 t0[4], t1[4];
    #pragma unroll
    for (int kt = 0; kt < 4; ++kt) {
        t0[kt] = *reinterpret_cast<const bf16x8*>(abufA + swz(jloc, kt * 64 + rgrp * 16));
        t1[kt] = *reinterpret_cast<const bf16x8*>(abufB + swz(jloc, kt * 64 + rgrp * 16));
    }
    LDS_FENCE();

    f32x4 f0 = {0.f, 0.f, 0.f, 0.f};
    f32x4 f1 = {0.f, 0.f, 0.f, 0.f};
    #pragma unroll
    for (int kt = 0; kt < 4; ++kt) {
        bf16x8 w3f = *reinterpret_cast<const bf16x8*>(
            wsB + 32768 + (size_t)(kt * 64 + lane) * 8);
        f0 = __builtin_amdgcn_mfma_f32_16x16x32_bf16(t0[kt], w3f, f0, 0, 0, 0);
        f1 = __builtin_amdgcn_mfma_f32_16x16x32_bf16(t1[kt], w3f, f1, 0, 0, 0);
    }

    if (jloc < 5) {
        #pragma unroll
        for (int q = 0; q < 4; ++q) {
            int row = rgrp * 4 + q;                // = vector index v
            float tA = f0[q];
            float tB = f1[q];
            if (row == 0) { float bb = b3[jloc]; tA += bb; tB += bb; }
            combA[row * 5 + jloc] = tA;            // rows 0..15 -> slots 0..79
            combB[row * 5 + jloc] = tB;
        }
    }
    if (lane == 63) { combA[80] = 0.f; combA[81] = 1.f; combB[80] = 0.f; combB[81] = 1.f; }
    LDS_FENCE();   // comb stores -> table reads

    // ---------------- table-driven writer: 38 outputs per sample ------------
    if (lane < 38) {
        OSpec sp = g_ospec[lane];
        float a1v = (combA[sp.a0] + combA[sp.a1] + combA[sp.a2]) * combA[sp.m] * sp.s1;
        float a2v = (combA[sp.b0] + combA[sp.b1] + combA[sp.b2]) * combA[sp.m2] * sp.s2;
        out[sp.base * nb + bA * sp.mul + sp.off] = a1v + a2v;
        float c1v = (combB[sp.a0] + combB[sp.a1] + combB[sp.a2]) * combB[sp.m] * sp.s1;
        float c2v = (combB[sp.b0] + combB[sp.b1] + combB[sp.b2]) * combB[sp.m2] * sp.s2;
        out[sp.base * nb + bB * sp.mul + sp.off] = c1v + c2v;
    }
}

} // namespace

extern "C" void kernel_launch(void* const* d_in, const int* in_sizes, int n_in,
                              void* d_out, int out_size, void* d_ws, size_t ws_size,
                              hipStream_t stream) {
    const float* x  = (const float*)d_in[0];
    const float* W0 = (const float*)d_in[1];
    const float* b0 = (const float*)d_in[2];
    const float* W1 = (const float*)d_in[3];
    const float* b1 = (const float*)d_in[4];
    const float* W2 = (const float*)d_in[5];
    const float* b2 = (const float*)d_in[6];
    const float* W3 = (const float*)d_in[7];
    const float* b3 = (const float*)d_in[8];
    float* out = (float*)d_out;
    unsigned short* wsB = (unsigned short*)d_ws;   // ~68 KB used

    const int nb = in_sizes[0] / 4;                // 32768
    pack_w_kernel<<<136, 256, 0, stream>>>(W1, W2, W3, wsB);
    const int blocks = (nb + 7) / 8;               // 8 samples (4 waves x 2) per block
    mlp_pde_kernel<<<blocks, 256, 0, stream>>>(x, W0, b0, b1, b2, b3, wsB, out, nb);
}

// Round 8
// 82.924 us; speedup vs baseline: 1.3976x; 1.0700x over previous
//
#include <hip/hip_runtime.h>
#include <hip/hip_bf16.h>

// GradientLayer: 4->128->128->128->5 tanh MLP; per-sample Jacobian (5x4) and
// Hessians of outputs 0 and 4, combined into 17 outputs.
// Round 8 (from validated round 7):
//  - nt-loop fully unrolled (was #pragma unroll 1): lets the scheduler hoist
//    the per-step swizzled-store / bfrag addressing (measured ~3x VALU-issue
//    fat vs algorithmic op count) and overlap next-step bfrag L2 latency
//    (~200cy) under current-step shfl->tanh->recomb.
//  - bf16 packing via native __bf16 casts -> v_cvt_pk_bf16_f32 (the
//    __float22bfloat162_rn header path is a ~9-op software RNE twiddle).
//  - Everything else identical to round 7 (dual-sample wave, VGPR cap 128).

namespace {

constexpr int HID = 128;

using bf16x8 = __attribute__((ext_vector_type(8))) short;
using f32x4  = __attribute__((ext_vector_type(4))) float;
typedef unsigned       __attribute__((may_alias)) u32a;
typedef unsigned short __attribute__((may_alias)) u16a;

#define LDS_FENCE() asm volatile("" ::: "memory")

struct OSpec {
    int base, mul, off;
    int a0, a1, a2, m;
    int b0, b1, b2, m2;
    float s1, s2;
};

// comb[] indices: value (v,k) at v*5+k, v in 0..14, k in 0..4.
// o_k = comb[k]; J[k][d] = comb[5+5d+k];
// Hn[p] = comb[25+5p]; HFi[p] = comb[29+5p]; comb[80]=0, comb[81]=1.
__constant__ OSpec g_ospec[38] = {
    {0,1,0,   0,80,80,81, 80,80,80,81, 1.f,0.f},   // n
    {1,1,0,   5,80,80,81, 80,80,80,81, 1.f,0.f},   // n_t
    {2,3,0,  10,80,80,81, 80,80,80,81, 1.f,0.f},   // n_grd
    {2,3,1,  15,80,80,81, 80,80,80,81, 1.f,0.f},
    {2,3,2,  20,80,80,81, 80,80,80,81, 1.f,0.f},
    {5,3,0,   1,80,80, 0, 80,80,80,81, 1.f,0.f},   // j = n*v
    {5,3,1,   2,80,80, 0, 80,80,80,81, 1.f,0.f},
    {5,3,2,   3,80,80, 0, 80,80,80,81, 1.f,0.f},
    {8,3,0,  10,15,20, 1, 11,16,21, 0, 1.f,1.f},   // j_div
    {8,3,1,  10,15,20, 2, 12,17,22, 0, 1.f,1.f},
    {8,3,2,  10,15,20, 3, 13,18,23, 0, 1.f,1.f},
    {11,1,0,  4,80,80,81, 80,80,80,81, 1.f,0.f},   // Fi
    {12,3,0, 14,80,80,81, 80,80,80,81, 1.f,0.f},   // Fi_grd
    {12,3,1, 19,80,80,81, 80,80,80,81, 1.f,0.f},
    {12,3,2, 24,80,80,81, 80,80,80,81, 1.f,0.f},
    {15,4,0, 34,39,44,81, 80,80,80,81, 1.f,0.f},   // Fi_lap (HFi p=1,2,3)
    {15,4,1, 49,54,59,81, 80,80,80,81, 1.f,0.f},   //        (p=4,5,6)
    {15,4,2, 54,64,69,81, 80,80,80,81, 1.f,0.f},   //        (p=5,7,8)
    {15,4,3, 59,69,74,81, 80,80,80,81, 1.f,0.f},   //        (p=6,8,9)
    {19,3,0,  1,80,80,81, 80,80,80,81, 1.f,0.f},   // v
    {19,3,1,  2,80,80,81, 80,80,80,81, 1.f,0.f},
    {19,3,2,  3,80,80,81, 80,80,80,81, 1.f,0.f},
    {22,1,0,  5,80,80,81, 80,80,80,81, 1.f,0.f},   // v_t
    {23,3,0,  1,80,80,10, 80,80,80,81, 1.f,0.f},   // v_adv
    {23,3,1,  2,80,80,15, 80,80,80,81, 1.f,0.f},
    {23,3,2,  3,80,80,20, 80,80,80,81, 1.f,0.f},
    {26,1,0, 30,50,65,81, 80,80,80,81, 1.f,0.f},   // v_lap (Hn p=1,5,8)
    {27,3,0, 45,50,55,81, 80,80,80,81, 1.f,0.f},   // v_div_grd (p=4,5,6)
    {27,3,1, 50,60,65,81, 80,80,80,81, 1.f,0.f},   //           (p=5,7,8)
    {27,3,2, 55,65,70,81, 80,80,80,81, 1.f,0.f},   //           (p=6,8,9)
    {30,1,0,  0,80,80,81, 80,80,80,81, 2.f,0.f},   // ro = 2n
    {31,1,0,  5,80,80,81, 80,80,80,81, 2.f,0.f},   // ro_t
    {32,3,0, 10,80,80,81, 80,80,80,81, 2.f,0.f},   // ro_grd
    {32,3,1, 15,80,80,81, 80,80,80,81, 2.f,0.f},
    {32,3,2, 20,80,80,81, 80,80,80,81, 2.f,0.f},
    {35,3,0, 10,15,20, 1, 11,16,21, 0, 2.f,2.f},   // rov_div
    {35,3,1, 10,15,20, 2, 12,17,22, 0, 2.f,2.f},
    {35,3,2, 10,15,20, 3, 13,18,23, 0, 2.f,2.f},
};

__device__ __forceinline__ unsigned short f2bf(float f) {
    union { float f; unsigned u; } v; v.f = f;
    unsigned r = v.u + 0x7FFFu + ((v.u >> 16) & 1u);   // RNE (cold path only)
    return (unsigned short)(r >> 16);
}
// hot-path pack: native casts -> v_cvt_pk_bf16_f32
__device__ __forceinline__ unsigned pk_bf16(float lo, float hi) {
    __bf16 l = (__bf16)lo;
    __bf16 h = (__bf16)hi;
    unsigned short ul, uh;
    __builtin_memcpy(&ul, &l, 2);
    __builtin_memcpy(&uh, &h, 2);
    return (unsigned)ul | ((unsigned)uh << 16);
}
__device__ __forceinline__ float tanh_fast(float z) {
    float e = __builtin_amdgcn_exp2f(z * 2.8853900817779268f);
    return 1.0f - 2.0f * __builtin_amdgcn_rcpf(e + 1.0f);
}
// swizzled byte offset inside a per-sample [16][128] bf16 A-buffer
__device__ __forceinline__ int swz(int row, int byte_in_row) {
    return (row * 256 + byte_in_row) ^ ((row & 7) << 4);
}

// ---- pack W1/W2 (+ W3 padded to 16 cols) into B-fragment bf16 in d_ws ------
__global__ void pack_w_kernel(const float* __restrict__ W1,
                              const float* __restrict__ W2,
                              const float* __restrict__ W3,
                              unsigned short* __restrict__ wsB) {
    int t = blockIdx.x * 256 + threadIdx.x;        // 0..34815
    if (t < 32768) {
        int reg  = t & 7;
        int lane = (t >> 3) & 63;
        int nt   = (t >> 9) & 7;
        int kt   = (t >> 12) & 3;
        int layer = (t >> 14) & 1;
        int k = kt * 32 + (lane >> 4) * 8 + reg;
        int n = nt * 16 + (lane & 15);
        const float* W = layer ? W2 : W1;
        wsB[t] = f2bf(W[k * HID + n]);
    } else if (t < 34816) {
        int tt = t - 32768;
        int reg  = tt & 7;
        int lane = (tt >> 3) & 63;
        int kt   = (tt >> 9) & 3;
        int k = kt * 32 + (lane >> 4) * 8 + reg;
        int n = lane & 15;
        wsB[t] = (n < 5) ? f2bf(W3[k * 5 + n]) : (unsigned short)0;
    }
}

__global__ __launch_bounds__(256, 4) void mlp_pde_kernel(
    const float* __restrict__ x,
    const float* __restrict__ W0, const float* __restrict__ b0,
    const float* __restrict__ b1, const float* __restrict__ b2,
    const float* __restrict__ b3,
    const unsigned short* __restrict__ wsB,
    float* __restrict__ out, int nb)
{
    constexpr int PD[10] = {0,0,0,0,1,1,1,2,2,3};
    constexpr int PE[10] = {0,1,2,3,1,2,3,2,3,3};

    __shared__ float lds[4][2304];                 // 9216 B per wave, 36864 B/block
    const int wave = threadIdx.x >> 6;
    const int lane = threadIdx.x & 63;
    float* wbase = lds[wave];
    char* abufA = (char*)wbase;                    // [16][128] bf16, swizzled
    char* abufB = (char*)wbase + 4096;
    float* combA = wbase + 2048;                   // 82 slots
    float* combB = wbase + 2176;                   // 82 slots
    int bA = blockIdx.x * 8 + wave * 2;
    int bB = bA + 1;
    if (bA >= nb) bA = nb - 1;
    if (bB >= nb) bB = nb - 1;

    // ---------------- layer 0 (4 -> 128), fp32, lane owns cols 2l,2l+1 ------
    {
        const int j0 = lane * 2;
        float w0d[4][2];
        #pragma unroll
        for (int d = 0; d < 4; ++d) {
            float2 w = *reinterpret_cast<const float2*>(W0 + d * HID + j0);
            w0d[d][0] = w.x; w0d[d][1] = w.y;
        }
        const float2 bb0 = *reinterpret_cast<const float2*>(b0 + j0);
        const float4 xvA = *reinterpret_cast<const float4*>(x + 4 * bA);
        const float4 xvB = *reinterpret_cast<const float4*>(x + 4 * bB);
        #pragma unroll
        for (int s = 0; s < 2; ++s) {
            const float4 xv = s ? xvB : xvA;
            char* abuf = s ? abufB : abufA;
            float val[15][2];
            #pragma unroll
            for (int jj = 0; jj < 2; ++jj) {
                float z = ((jj == 0) ? bb0.x : bb0.y)
                        + xv.x * w0d[0][jj] + xv.y * w0d[1][jj]
                        + xv.z * w0d[2][jj] + xv.w * w0d[3][jj];
                float h = tanh_fast(z);
                float sd = 1.f - h * h;
                val[0][jj] = h;
                #pragma unroll
                for (int d = 0; d < 4; ++d) val[1 + d][jj] = sd * w0d[d][jj];
                #pragma unroll
                for (int p = 0; p < 10; ++p)
                    val[5 + p][jj] = -2.f * h * sd * w0d[PD[p]][jj] * w0d[PE[p]][jj];
            }
            #pragma unroll
            for (int v = 0; v < 15; ++v)
                *reinterpret_cast<u32a*>(abuf + swz(v, j0 * 2)) = pk_bf16(val[v][0], val[v][1]);
            *reinterpret_cast<u32a*>(abuf + swz(15, j0 * 2)) = 0u;  // pad row
        }
    }
    LDS_FENCE();   // layer-0 stores -> afrag reads

    // ---------------- layers 1,2 via MFMA (dual sample) ---------------------
    const int jloc = lane & 15;                    // column within 16-wide tile
    const int rgrp = lane >> 4;                    // row group: rows 4r..4r+3

    // chain-rule recombination on the C/D layout; writes new A-tile rows
    auto recomb = [&](const f32x4& acc, char* abuf, float bnt, int nt) {
        float z0 = __shfl(acc[0], jloc, 64);       // row 0 (primal z)
        float u0 = __shfl(acc[1], jloc, 64);       // row 1 (dz_0)
        float u1 = __shfl(acc[2], jloc, 64);       // row 2 (dz_1)
        float u2 = __shfl(acc[3], jloc, 64);       // row 3 (dz_2)
        float u3 = __shfl(acc[0], jloc + 16, 64);  // row 4 (dz_3)
        float h = tanh_fast(z0 + bnt);
        float s = 1.f - h * h;
        float c = -2.f * h * s;
        float nv[4];
        if (rgrp == 0) {
            nv[0] = h;           nv[1] = s * u0;
            nv[2] = s * u1;      nv[3] = s * u2;
        } else if (rgrp == 1) {
            nv[0] = s * u3;
            nv[1] = fmaf(c * u0, u0, s * acc[1]);  // row 5  (0,0)
            nv[2] = fmaf(c * u0, u1, s * acc[2]);  // row 6  (0,1)
            nv[3] = fmaf(c * u0, u2, s * acc[3]);  // row 7  (0,2)
        } else if (rgrp == 2) {
            nv[0] = fmaf(c * u0, u3, s * acc[0]);  // row 8  (0,3)
            nv[1] = fmaf(c * u1, u1, s * acc[1]);  // row 9  (1,1)
            nv[2] = fmaf(c * u1, u2, s * acc[2]);  // row 10 (1,2)
            nv[3] = fmaf(c * u1, u3, s * acc[3]);  // row 11 (1,3)
        } else {
            nv[0] = fmaf(c * u2, u2, s * acc[0]);  // row 12 (2,2)
            nv[1] = fmaf(c * u2, u3, s * acc[1]);  // row 13 (2,3)
            nv[2] = fmaf(c * u3, u3, s * acc[2]);  // row 14 (3,3)
            nv[3] = 0.f;                           // pad row 15
        }
        unsigned pk01 = pk_bf16(nv[0], nv[1]);
        unsigned pk23 = pk_bf16(nv[2], nv[3]);
        const int bcol = (nt * 16 + jloc) * 2;
        *reinterpret_cast<u16a*>(abuf + swz(rgrp * 4 + 0, bcol)) = (unsigned short)pk01;
        *reinterpret_cast<u16a*>(abuf + swz(rgrp * 4 + 1, bcol)) = (unsigned short)(pk01 >> 16);
        *reinterpret_cast<u16a*>(abuf + swz(rgrp * 4 + 2, bcol)) = (unsigned short)pk23;
        *reinterpret_cast<u16a*>(abuf + swz(rgrp * 4 + 3, bcol)) = (unsigned short)(pk23 >> 16);
    };

    #pragma unroll 1
    for (int layer = 0; layer < 2; ++layer) {
        // A fragments: lane holds A[m = lane&15][k = kt*32 + (lane>>4)*8 + 0..7]
        bf16x8 a0[4], a1[4];
        #pragma unroll
        for (int kt = 0; kt < 4; ++kt) {
            a0[kt] = *reinterpret_cast<const bf16x8*>(abufA + swz(jloc, kt * 64 + rgrp * 16));
            a1[kt] = *reinterpret_cast<const bf16x8*>(abufB + swz(jloc, kt * 64 + rgrp * 16));
        }
        LDS_FENCE();   // afrag reads -> recombination stores (WAR)
        const float* bias = layer ? b2 : b1;
        float bv[8];
        #pragma unroll
        for (int nt = 0; nt < 8; ++nt) bv[nt] = bias[nt * 16 + jloc];

        #pragma unroll
        for (int nt = 0; nt < 8; ++nt) {
            f32x4 acc0 = {0.f, 0.f, 0.f, 0.f};
            f32x4 acc1 = {0.f, 0.f, 0.f, 0.f};
            #pragma unroll
            for (int kt = 0; kt < 4; ++kt) {
                bf16x8 bfrag = *reinterpret_cast<const bf16x8*>(
                    wsB + ((size_t)((layer * 4 + kt) * 8 + nt) * 512 + lane * 8));
                acc0 = __builtin_amdgcn_mfma_f32_16x16x32_bf16(a0[kt], bfrag, acc0, 0, 0, 0);
                acc1 = __builtin_amdgcn_mfma_f32_16x16x32_bf16(a1[kt], bfrag, acc1, 0, 0, 0);
            }
            recomb(acc0, abufA, bv[nt], nt);
            recomb(acc1, abufB, bv[nt], nt);
        }
        LDS_FENCE();   // recombination stores -> next-layer / epilogue reads
    }

    // ---------------- epilogue: T(16x128) @ W3pad(128x16) via MFMA ----------
    bf16x8 t0[4], t1[4];
    #pragma unroll
    for (int kt = 0; kt < 4; ++kt) {
        t0[kt] = *reinterpret_cast<const bf16x8*>(abufA + swz(jloc, kt * 64 + rgrp * 16));
        t1[kt] = *reinterpret_cast<const bf16x8*>(abufB + swz(jloc, kt * 64 + rgrp * 16));
    }
    LDS_FENCE();

    f32x4 f0 = {0.f, 0.f, 0.f, 0.f};
    f32x4 f1 = {0.f, 0.f, 0.f, 0.f};
    #pragma unroll
    for (int kt = 0; kt < 4; ++kt) {
        bf16x8 w3f = *reinterpret_cast<const bf16x8*>(
            wsB + 32768 + (size_t)(kt * 64 + lane) * 8);
        f0 = __builtin_amdgcn_mfma_f32_16x16x32_bf16(t0[kt], w3f, f0, 0, 0, 0);
        f1 = __builtin_amdgcn_mfma_f32_16x16x32_bf16(t1[kt], w3f, f1, 0, 0, 0);
    }

    if (jloc < 5) {
        #pragma unroll
        for (int q = 0; q < 4; ++q) {
            int row = rgrp * 4 + q;                // = vector index v
            float tA = f0[q];
            float tB = f1[q];
            if (row == 0) { float bb = b3[jloc]; tA += bb; tB += bb; }
            combA[row * 5 + jloc] = tA;            // rows 0..15 -> slots 0..79
            combB[row * 5 + jloc] = tB;
        }
    }
    if (lane == 63) { combA[80] = 0.f; combA[81] = 1.f; combB[80] = 0.f; combB[81] = 1.f; }
    LDS_FENCE();   // comb stores -> table reads

    // ---------------- table-driven writer: 38 outputs per sample ------------
    if (lane < 38) {
        OSpec sp = g_ospec[lane];
        float a1v = (combA[sp.a0] + combA[sp.a1] + combA[sp.a2]) * combA[sp.m] * sp.s1;
        float a2v = (combA[sp.b0] + combA[sp.b1] + combA[sp.b2]) * combA[sp.m2] * sp.s2;
        out[sp.base * nb + bA * sp.mul + sp.off] = a1v + a2v;
        float c1v = (combB[sp.a0] + combB[sp.a1] + combB[sp.a2]) * combB[sp.m] * sp.s1;
        float c2v = (combB[sp.b0] + combB[sp.b1] + combB[sp.b2]) * combB[sp.m2] * sp.s2;
        out[sp.base * nb + bB * sp.mul + sp.off] = c1v + c2v;
    }
}

} // namespace

extern "C" void kernel_launch(void* const* d_in, const int* in_sizes, int n_in,
                              void* d_out, int out_size, void* d_ws, size_t ws_size,
                              hipStream_t stream) {
    const float* x  = (const float*)d_in[0];
    const float* W0 = (const float*)d_in[1];
    const float* b0 = (const float*)d_in[2];
    const float* W1 = (const float*)d_in[3];
    const float* b1 = (const float*)d_in[4];
    const float* W2 = (const float*)d_in[5];
    const float* b2 = (const float*)d_in[6];
    const float* W3 = (const float*)d_in[7];
    const float* b3 = (const float*)d_in[8];
    float* out = (float*)d_out;
    unsigned short* wsB = (unsigned short*)d_ws;   // ~68 KB used

    const int nb = in_sizes[0] / 4;                // 32768
    pack_w_kernel<<<136, 256, 0, stream>>>(W1, W2, W3, wsB);
    const int blocks = (nb + 7) / 8;               // 8 samples (4 waves x 2) per block
    mlp_pde_kernel<<<blocks, 256, 0, stream>>>(x, W0, b0, b1, b2, b3, wsB, out, nb);
}

// Round 9
// 82.830 us; speedup vs baseline: 1.3992x; 1.0011x over previous
//
#include <hip/hip_runtime.h>
#include <hip/hip_bf16.h>

// GradientLayer: 4->128->128->128->5 tanh MLP; per-sample Jacobian (5x4) and
// Hessians of outputs 0 and 4, combined into 17 outputs.
// Round 9 (from validated round 8):
//  - LDS trim: comb buffers overlap the (dead-after-tfrag) abufA region.
//    Per-wave LDS 9216 -> 8192 B, block 36864 -> 32768 B -> 5 blocks/CU
//    (20 waves/CU, 62.5% cap, was 16/50%). Single-variable change; math
//    bit-identical to round 8.

namespace {

constexpr int HID = 128;

using bf16x8 = __attribute__((ext_vector_type(8))) short;
using f32x4  = __attribute__((ext_vector_type(4))) float;
typedef unsigned       __attribute__((may_alias)) u32a;
typedef unsigned short __attribute__((may_alias)) u16a;

#define LDS_FENCE() asm volatile("" ::: "memory")

struct OSpec {
    int base, mul, off;
    int a0, a1, a2, m;
    int b0, b1, b2, m2;
    float s1, s2;
};

// comb[] indices: value (v,k) at v*5+k, v in 0..14, k in 0..4.
// o_k = comb[k]; J[k][d] = comb[5+5d+k];
// Hn[p] = comb[25+5p]; HFi[p] = comb[29+5p]; comb[80]=0, comb[81]=1.
__constant__ OSpec g_ospec[38] = {
    {0,1,0,   0,80,80,81, 80,80,80,81, 1.f,0.f},   // n
    {1,1,0,   5,80,80,81, 80,80,80,81, 1.f,0.f},   // n_t
    {2,3,0,  10,80,80,81, 80,80,80,81, 1.f,0.f},   // n_grd
    {2,3,1,  15,80,80,81, 80,80,80,81, 1.f,0.f},
    {2,3,2,  20,80,80,81, 80,80,80,81, 1.f,0.f},
    {5,3,0,   1,80,80, 0, 80,80,80,81, 1.f,0.f},   // j = n*v
    {5,3,1,   2,80,80, 0, 80,80,80,81, 1.f,0.f},
    {5,3,2,   3,80,80, 0, 80,80,80,81, 1.f,0.f},
    {8,3,0,  10,15,20, 1, 11,16,21, 0, 1.f,1.f},   // j_div
    {8,3,1,  10,15,20, 2, 12,17,22, 0, 1.f,1.f},
    {8,3,2,  10,15,20, 3, 13,18,23, 0, 1.f,1.f},
    {11,1,0,  4,80,80,81, 80,80,80,81, 1.f,0.f},   // Fi
    {12,3,0, 14,80,80,81, 80,80,80,81, 1.f,0.f},   // Fi_grd
    {12,3,1, 19,80,80,81, 80,80,80,81, 1.f,0.f},
    {12,3,2, 24,80,80,81, 80,80,80,81, 1.f,0.f},
    {15,4,0, 34,39,44,81, 80,80,80,81, 1.f,0.f},   // Fi_lap (HFi p=1,2,3)
    {15,4,1, 49,54,59,81, 80,80,80,81, 1.f,0.f},   //        (p=4,5,6)
    {15,4,2, 54,64,69,81, 80,80,80,81, 1.f,0.f},   //        (p=5,7,8)
    {15,4,3, 59,69,74,81, 80,80,80,81, 1.f,0.f},   //        (p=6,8,9)
    {19,3,0,  1,80,80,81, 80,80,80,81, 1.f,0.f},   // v
    {19,3,1,  2,80,80,81, 80,80,80,81, 1.f,0.f},
    {19,3,2,  3,80,80,81, 80,80,80,81, 1.f,0.f},
    {22,1,0,  5,80,80,81, 80,80,80,81, 1.f,0.f},   // v_t
    {23,3,0,  1,80,80,10, 80,80,80,81, 1.f,0.f},   // v_adv
    {23,3,1,  2,80,80,15, 80,80,80,81, 1.f,0.f},
    {23,3,2,  3,80,80,20, 80,80,80,81, 1.f,0.f},
    {26,1,0, 30,50,65,81, 80,80,80,81, 1.f,0.f},   // v_lap (Hn p=1,5,8)
    {27,3,0, 45,50,55,81, 80,80,80,81, 1.f,0.f},   // v_div_grd (p=4,5,6)
    {27,3,1, 50,60,65,81, 80,80,80,81, 1.f,0.f},   //           (p=5,7,8)
    {27,3,2, 55,65,70,81, 80,80,80,81, 1.f,0.f},   //           (p=6,8,9)
    {30,1,0,  0,80,80,81, 80,80,80,81, 2.f,0.f},   // ro = 2n
    {31,1,0,  5,80,80,81, 80,80,80,81, 2.f,0.f},   // ro_t
    {32,3,0, 10,80,80,81, 80,80,80,81, 2.f,0.f},   // ro_grd
    {32,3,1, 15,80,80,81, 80,80,80,81, 2.f,0.f},
    {32,3,2, 20,80,80,81, 80,80,80,81, 2.f,0.f},
    {35,3,0, 10,15,20, 1, 11,16,21, 0, 2.f,2.f},   // rov_div
    {35,3,1, 10,15,20, 2, 12,17,22, 0, 2.f,2.f},
    {35,3,2, 10,15,20, 3, 13,18,23, 0, 2.f,2.f},
};

__device__ __forceinline__ unsigned short f2bf(float f) {
    union { float f; unsigned u; } v; v.f = f;
    unsigned r = v.u + 0x7FFFu + ((v.u >> 16) & 1u);   // RNE (cold path only)
    return (unsigned short)(r >> 16);
}
// hot-path pack: native casts -> v_cvt_pk_bf16_f32
__device__ __forceinline__ unsigned pk_bf16(float lo, float hi) {
    __bf16 l = (__bf16)lo;
    __bf16 h = (__bf16)hi;
    unsigned short ul, uh;
    __builtin_memcpy(&ul, &l, 2);
    __builtin_memcpy(&uh, &h, 2);
    return (unsigned)ul | ((unsigned)uh << 16);
}
__device__ __forceinline__ float tanh_fast(float z) {
    float e = __builtin_amdgcn_exp2f(z * 2.8853900817779268f);
    return 1.0f - 2.0f * __builtin_amdgcn_rcpf(e + 1.0f);
}
// swizzled byte offset inside a per-sample [16][128] bf16 A-buffer
__device__ __forceinline__ int swz(int row, int byte_in_row) {
    return (row * 256 + byte_in_row) ^ ((row & 7) << 4);
}

// ---- pack W1/W2 (+ W3 padded to 16 cols) into B-fragment bf16 in d_ws ------
__global__ void pack_w_kernel(const float* __restrict__ W1,
                              const float* __restrict__ W2,
                              const float* __restrict__ W3,
                              unsigned short* __restrict__ wsB) {
    int t = blockIdx.x * 256 + threadIdx.x;        // 0..34815
    if (t < 32768) {
        int reg  = t & 7;
        int lane = (t >> 3) & 63;
        int nt   = (t >> 9) & 7;
        int kt   = (t >> 12) & 3;
        int layer = (t >> 14) & 1;
        int k = kt * 32 + (lane >> 4) * 8 + reg;
        int n = nt * 16 + (lane & 15);
        const float* W = layer ? W2 : W1;
        wsB[t] = f2bf(W[k * HID + n]);
    } else if (t < 34816) {
        int tt = t - 32768;
        int reg  = tt & 7;
        int lane = (tt >> 3) & 63;
        int kt   = (tt >> 9) & 3;
        int k = kt * 32 + (lane >> 4) * 8 + reg;
        int n = lane & 15;
        wsB[t] = (n < 5) ? f2bf(W3[k * 5 + n]) : (unsigned short)0;
    }
}

__global__ __launch_bounds__(256, 4) void mlp_pde_kernel(
    const float* __restrict__ x,
    const float* __restrict__ W0, const float* __restrict__ b0,
    const float* __restrict__ b1, const float* __restrict__ b2,
    const float* __restrict__ b3,
    const unsigned short* __restrict__ wsB,
    float* __restrict__ out, int nb)
{
    constexpr int PD[10] = {0,0,0,0,1,1,1,2,2,3};
    constexpr int PE[10] = {0,1,2,3,1,2,3,2,3,3};

    __shared__ float lds[4][2048];                 // 8192 B per wave, 32768 B/block
    const int wave = threadIdx.x >> 6;
    const int lane = threadIdx.x & 63;
    float* wbase = lds[wave];
    char* abufA = (char*)wbase;                    // [16][128] bf16, swizzled
    char* abufB = (char*)wbase + 4096;
    float* combA = wbase;                          // overlaps abufA (dead after tfrag)
    float* combB = wbase + 82;
    int bA = blockIdx.x * 8 + wave * 2;
    int bB = bA + 1;
    if (bA >= nb) bA = nb - 1;
    if (bB >= nb) bB = nb - 1;

    // ---------------- layer 0 (4 -> 128), fp32, lane owns cols 2l,2l+1 ------
    {
        const int j0 = lane * 2;
        float w0d[4][2];
        #pragma unroll
        for (int d = 0; d < 4; ++d) {
            float2 w = *reinterpret_cast<const float2*>(W0 + d * HID + j0);
            w0d[d][0] = w.x; w0d[d][1] = w.y;
        }
        const float2 bb0 = *reinterpret_cast<const float2*>(b0 + j0);
        const float4 xvA = *reinterpret_cast<const float4*>(x + 4 * bA);
        const float4 xvB = *reinterpret_cast<const float4*>(x + 4 * bB);
        #pragma unroll
        for (int s = 0; s < 2; ++s) {
            const float4 xv = s ? xvB : xvA;
            char* abuf = s ? abufB : abufA;
            float val[15][2];
            #pragma unroll
            for (int jj = 0; jj < 2; ++jj) {
                float z = ((jj == 0) ? bb0.x : bb0.y)
                        + xv.x * w0d[0][jj] + xv.y * w0d[1][jj]
                        + xv.z * w0d[2][jj] + xv.w * w0d[3][jj];
                float h = tanh_fast(z);
                float sd = 1.f - h * h;
                val[0][jj] = h;
                #pragma unroll
                for (int d = 0; d < 4; ++d) val[1 + d][jj] = sd * w0d[d][jj];
                #pragma unroll
                for (int p = 0; p < 10; ++p)
                    val[5 + p][jj] = -2.f * h * sd * w0d[PD[p]][jj] * w0d[PE[p]][jj];
            }
            #pragma unroll
            for (int v = 0; v < 15; ++v)
                *reinterpret_cast<u32a*>(abuf + swz(v, j0 * 2)) = pk_bf16(val[v][0], val[v][1]);
            *reinterpret_cast<u32a*>(abuf + swz(15, j0 * 2)) = 0u;  // pad row
        }
    }
    LDS_FENCE();   // layer-0 stores -> afrag reads

    // ---------------- layers 1,2 via MFMA (dual sample) ---------------------
    const int jloc = lane & 15;                    // column within 16-wide tile
    const int rgrp = lane >> 4;                    // row group: rows 4r..4r+3

    // chain-rule recombination on the C/D layout; writes new A-tile rows
    auto recomb = [&](const f32x4& acc, char* abuf, float bnt, int nt) {
        float z0 = __shfl(acc[0], jloc, 64);       // row 0 (primal z)
        float u0 = __shfl(acc[1], jloc, 64);       // row 1 (dz_0)
        float u1 = __shfl(acc[2], jloc, 64);       // row 2 (dz_1)
        float u2 = __shfl(acc[3], jloc, 64);       // row 3 (dz_2)
        float u3 = __shfl(acc[0], jloc + 16, 64);  // row 4 (dz_3)
        float h = tanh_fast(z0 + bnt);
        float s = 1.f - h * h;
        float c = -2.f * h * s;
        float nv[4];
        if (rgrp == 0) {
            nv[0] = h;           nv[1] = s * u0;
            nv[2] = s * u1;      nv[3] = s * u2;
        } else if (rgrp == 1) {
            nv[0] = s * u3;
            nv[1] = fmaf(c * u0, u0, s * acc[1]);  // row 5  (0,0)
            nv[2] = fmaf(c * u0, u1, s * acc[2]);  // row 6  (0,1)
            nv[3] = fmaf(c * u0, u2, s * acc[3]);  // row 7  (0,2)
        } else if (rgrp == 2) {
            nv[0] = fmaf(c * u0, u3, s * acc[0]);  // row 8  (0,3)
            nv[1] = fmaf(c * u1, u1, s * acc[1]);  // row 9  (1,1)
            nv[2] = fmaf(c * u1, u2, s * acc[2]);  // row 10 (1,2)
            nv[3] = fmaf(c * u1, u3, s * acc[3]);  // row 11 (1,3)
        } else {
            nv[0] = fmaf(c * u2, u2, s * acc[0]);  // row 12 (2,2)
            nv[1] = fmaf(c * u2, u3, s * acc[1]);  // row 13 (2,3)
            nv[2] = fmaf(c * u3, u3, s * acc[2]);  // row 14 (3,3)
            nv[3] = 0.f;                           // pad row 15
        }
        unsigned pk01 = pk_bf16(nv[0], nv[1]);
        unsigned pk23 = pk_bf16(nv[2], nv[3]);
        const int bcol = (nt * 16 + jloc) * 2;
        *reinterpret_cast<u16a*>(abuf + swz(rgrp * 4 + 0, bcol)) = (unsigned short)pk01;
        *reinterpret_cast<u16a*>(abuf + swz(rgrp * 4 + 1, bcol)) = (unsigned short)(pk01 >> 16);
        *reinterpret_cast<u16a*>(abuf + swz(rgrp * 4 + 2, bcol)) = (unsigned short)pk23;
        *reinterpret_cast<u16a*>(abuf + swz(rgrp * 4 + 3, bcol)) = (unsigned short)(pk23 >> 16);
    };

    #pragma unroll 1
    for (int layer = 0; layer < 2; ++layer) {
        // A fragments: lane holds A[m = lane&15][k = kt*32 + (lane>>4)*8 + 0..7]
        bf16x8 a0[4], a1[4];
        #pragma unroll
        for (int kt = 0; kt < 4; ++kt) {
            a0[kt] = *reinterpret_cast<const bf16x8*>(abufA + swz(jloc, kt * 64 + rgrp * 16));
            a1[kt] = *reinterpret_cast<const bf16x8*>(abufB + swz(jloc, kt * 64 + rgrp * 16));
        }
        LDS_FENCE();   // afrag reads -> recombination stores (WAR)
        const float* bias = layer ? b2 : b1;
        float bv[8];
        #pragma unroll
        for (int nt = 0; nt < 8; ++nt) bv[nt] = bias[nt * 16 + jloc];

        #pragma unroll
        for (int nt = 0; nt < 8; ++nt) {
            f32x4 acc0 = {0.f, 0.f, 0.f, 0.f};
            f32x4 acc1 = {0.f, 0.f, 0.f, 0.f};
            #pragma unroll
            for (int kt = 0; kt < 4; ++kt) {
                bf16x8 bfrag = *reinterpret_cast<const bf16x8*>(
                    wsB + ((size_t)((layer * 4 + kt) * 8 + nt) * 512 + lane * 8));
                acc0 = __builtin_amdgcn_mfma_f32_16x16x32_bf16(a0[kt], bfrag, acc0, 0, 0, 0);
                acc1 = __builtin_amdgcn_mfma_f32_16x16x32_bf16(a1[kt], bfrag, acc1, 0, 0, 0);
            }
            recomb(acc0, abufA, bv[nt], nt);
            recomb(acc1, abufB, bv[nt], nt);
        }
        LDS_FENCE();   // recombination stores -> next-layer / epilogue reads
    }

    // ---------------- epilogue: T(16x128) @ W3pad(128x16) via MFMA ----------
    bf16x8 t0[4], t1[4];
    #pragma unroll
    for (int kt = 0; kt < 4; ++kt) {
        t0[kt] = *reinterpret_cast<const bf16x8*>(abufA + swz(jloc, kt * 64 + rgrp * 16));
        t1[kt] = *reinterpret_cast<const bf16x8*>(abufB + swz(jloc, kt * 64 + rgrp * 16));
    }
    LDS_FENCE();   // tfrag reads -> comb stores (comb overlaps abufA)

    f32x4 f0 = {0.f, 0.f, 0.f, 0.f};
    f32x4 f1 = {0.f, 0.f, 0.f, 0.f};
    #pragma unroll
    for (int kt = 0; kt < 4; ++kt) {
        bf16x8 w3f = *reinterpret_cast<const bf16x8*>(
            wsB + 32768 + (size_t)(kt * 64 + lane) * 8);
        f0 = __builtin_amdgcn_mfma_f32_16x16x32_bf16(t0[kt], w3f, f0, 0, 0, 0);
        f1 = __builtin_amdgcn_mfma_f32_16x16x32_bf16(t1[kt], w3f, f1, 0, 0, 0);
    }

    if (jloc < 5) {
        #pragma unroll
        for (int q = 0; q < 4; ++q) {
            int row = rgrp * 4 + q;                // = vector index v
            float tA = f0[q];
            float tB = f1[q];
            if (row == 0) { float bb = b3[jloc]; tA += bb; tB += bb; }
            combA[row * 5 + jloc] = tA;            // rows 0..15 -> slots 0..79
            combB[row * 5 + jloc] = tB;
        }
    }
    if (lane == 63) { combA[80] = 0.f; combA[81] = 1.f; combB[80] = 0.f; combB[81] = 1.f; }
    LDS_FENCE();   // comb stores -> table reads

    // ---------------- table-driven writer: 38 outputs per sample ------------
    if (lane < 38) {
        OSpec sp = g_ospec[lane];
        float a1v = (combA[sp.a0] + combA[sp.a1] + combA[sp.a2]) * combA[sp.m] * sp.s1;
        float a2v = (combA[sp.b0] + combA[sp.b1] + combA[sp.b2]) * combA[sp.m2] * sp.s2;
        out[sp.base * nb + bA * sp.mul + sp.off] = a1v + a2v;
        float c1v = (combB[sp.a0] + combB[sp.a1] + combB[sp.a2]) * combB[sp.m] * sp.s1;
        float c2v = (combB[sp.b0] + combB[sp.b1] + combB[sp.b2]) * combB[sp.m2] * sp.s2;
        out[sp.base * nb + bB * sp.mul + sp.off] = c1v + c2v;
    }
}

} // namespace

extern "C" void kernel_launch(void* const* d_in, const int* in_sizes, int n_in,
                              void* d_out, int out_size, void* d_ws, size_t ws_size,
                              hipStream_t stream) {
    const float* x  = (const float*)d_in[0];
    const float* W0 = (const float*)d_in[1];
    const float* b0 = (const float*)d_in[2];
    const float* W1 = (const float*)d_in[3];
    const float* b1 = (const float*)d_in[4];
    const float* W2 = (const float*)d_in[5];
    const float* b2 = (const float*)d_in[6];
    const float* W3 = (const float*)d_in[7];
    const float* b3 = (const float*)d_in[8];
    float* out = (float*)d_out;
    unsigned short* wsB = (unsigned short*)d_ws;   // ~68 KB used

    const int nb = in_sizes[0] / 4;                // 32768
    pack_w_kernel<<<136, 256, 0, stream>>>(W1, W2, W3, wsB);
    const int blocks = (nb + 7) / 8;               // 8 samples (4 waves x 2) per block
    mlp_pde_kernel<<<blocks, 256, 0, stream>>>(x, W0, b0, b1, b2, b3, wsB, out, nb);
}

// Round 10
// 81.787 us; speedup vs baseline: 1.4171x; 1.0128x over previous
//
#include <hip/hip_runtime.h>
#include <hip/hip_bf16.h>

// GradientLayer: 4->128->128->128->5 tanh MLP; per-sample Jacobian (5x4) and
// Hessians of outputs 0 and 4, combined into 17 outputs.
// Round 10 (from validated round 9):
//  - 32x32x16 MFMA, both samples stacked (A rows 0-15 = sample A vectors,
//    16-31 = sample B). Per layer: 32 MFMA (was 64 issues), 40 bpermutes
//    (was 80), 8 tanh (was 16).
//  - Vector->row PERMUTATION chosen so each acc-reg's (hi=0,hi=1) row pair
//    has the same formula shape -> recomb is branch-free cndmask selection.
//    Permutation folded into layer-0 ROWMAP + remapped OSpec table.
//  - C/D layout col=lane&31, row=(reg&3)+8(reg>>2)+4(lane>>5) [HW-verified].
//    A/B k-mapping k=(lane>>5)*8+reg (analog of validated 16x16x32 mapping).

namespace {

constexpr int HID = 128;

using bf16x8 = __attribute__((ext_vector_type(8))) short;
using f32x16 = __attribute__((ext_vector_type(16))) float;
typedef unsigned       __attribute__((may_alias)) u32a;
typedef unsigned short __attribute__((may_alias)) u16a;

#define LDS_FENCE() asm volatile("" ::: "memory")

struct OSpec {
    int base, mul, off;
    int a0, a1, a2, m;
    int b0, b1, b2, m2;
    float s1, s2;
};

// comb[] indexed by ROW (permuted): value at row*5+k.
// Row map sigma(v): {0:0,1:1,2:5,3:2,4:6,5:3,6:7,7:8,8:12,9:9,10:13,11:10,
// 12:14,13:11,14:15}. Indices below = sigma(v)*5+k of the validated table.
// comb[80]=0, comb[81]=1.
__constant__ OSpec g_ospec[38] = {
    {0,1,0,   0,80,80,81, 80,80,80,81, 1.f,0.f},   // n
    {1,1,0,   5,80,80,81, 80,80,80,81, 1.f,0.f},   // n_t
    {2,3,0,  25,80,80,81, 80,80,80,81, 1.f,0.f},   // n_grd (v2->row5)
    {2,3,1,  10,80,80,81, 80,80,80,81, 1.f,0.f},   //       (v3->row2)
    {2,3,2,  30,80,80,81, 80,80,80,81, 1.f,0.f},   //       (v4->row6)
    {5,3,0,   1,80,80, 0, 80,80,80,81, 1.f,0.f},   // j = n*v
    {5,3,1,   2,80,80, 0, 80,80,80,81, 1.f,0.f},
    {5,3,2,   3,80,80, 0, 80,80,80,81, 1.f,0.f},
    {8,3,0,  25,10,30, 1, 26,11,31, 0, 1.f,1.f},   // j_div
    {8,3,1,  25,10,30, 2, 27,12,32, 0, 1.f,1.f},
    {8,3,2,  25,10,30, 3, 28,13,33, 0, 1.f,1.f},
    {11,1,0,  4,80,80,81, 80,80,80,81, 1.f,0.f},   // Fi
    {12,3,0, 29,80,80,81, 80,80,80,81, 1.f,0.f},   // Fi_grd
    {12,3,1, 14,80,80,81, 80,80,80,81, 1.f,0.f},
    {12,3,2, 34,80,80,81, 80,80,80,81, 1.f,0.f},
    {15,4,0, 39,44,64,81, 80,80,80,81, 1.f,0.f},   // Fi_lap (HFi p=1,2,3)
    {15,4,1, 49,69,54,81, 80,80,80,81, 1.f,0.f},   //        (p=4,5,6)
    {15,4,2, 69,74,59,81, 80,80,80,81, 1.f,0.f},   //        (p=5,7,8)
    {15,4,3, 54,59,79,81, 80,80,80,81, 1.f,0.f},   //        (p=6,8,9)
    {19,3,0,  1,80,80,81, 80,80,80,81, 1.f,0.f},   // v
    {19,3,1,  2,80,80,81, 80,80,80,81, 1.f,0.f},
    {19,3,2,  3,80,80,81, 80,80,80,81, 1.f,0.f},
    {22,1,0,  5,80,80,81, 80,80,80,81, 1.f,0.f},   // v_t
    {23,3,0,  1,80,80,25, 80,80,80,81, 1.f,0.f},   // v_adv
    {23,3,1,  2,80,80,10, 80,80,80,81, 1.f,0.f},
    {23,3,2,  3,80,80,30, 80,80,80,81, 1.f,0.f},
    {26,1,0, 35,65,55,81, 80,80,80,81, 1.f,0.f},   // v_lap (Hn p=1,5,8)
    {27,3,0, 45,65,50,81, 80,80,80,81, 1.f,0.f},   // v_div_grd (p=4,5,6)
    {27,3,1, 65,70,55,81, 80,80,80,81, 1.f,0.f},   //           (p=5,7,8)
    {27,3,2, 50,55,75,81, 80,80,80,81, 1.f,0.f},   //           (p=6,8,9)
    {30,1,0,  0,80,80,81, 80,80,80,81, 2.f,0.f},   // ro = 2n
    {31,1,0,  5,80,80,81, 80,80,80,81, 2.f,0.f},   // ro_t
    {32,3,0, 25,80,80,81, 80,80,80,81, 2.f,0.f},   // ro_grd
    {32,3,1, 10,80,80,81, 80,80,80,81, 2.f,0.f},
    {32,3,2, 30,80,80,81, 80,80,80,81, 2.f,0.f},
    {35,3,0, 25,10,30, 1, 26,11,31, 0, 2.f,2.f},   // rov_div
    {35,3,1, 25,10,30, 2, 27,12,32, 0, 2.f,2.f},
    {35,3,2, 25,10,30, 3, 28,13,33, 0, 2.f,2.f},
};

__device__ __forceinline__ unsigned short f2bf(float f) {
    union { float f; unsigned u; } v; v.f = f;
    unsigned r = v.u + 0x7FFFu + ((v.u >> 16) & 1u);   // RNE (pack kernel only)
    return (unsigned short)(r >> 16);
}
__device__ __forceinline__ unsigned pk_bf16(float lo, float hi) {
    __bf16 l = (__bf16)lo;
    __bf16 h = (__bf16)hi;
    unsigned short ul, uh;
    __builtin_memcpy(&ul, &l, 2);
    __builtin_memcpy(&uh, &h, 2);
    return (unsigned)ul | ((unsigned)uh << 16);
}
__device__ __forceinline__ unsigned short bf1(float x) {
    __bf16 b = (__bf16)x;
    unsigned short u; __builtin_memcpy(&u, &b, 2); return u;
}
__device__ __forceinline__ float tanh_fast(float z) {
    float e = __builtin_amdgcn_exp2f(z * 2.8853900817779268f);
    return 1.0f - 2.0f * __builtin_amdgcn_rcpf(e + 1.0f);
}
// swizzled byte offset inside a per-sample [16][128] bf16 A-buffer
__device__ __forceinline__ int swz(int row, int byte_in_row) {
    return (row * 256 + byte_in_row) ^ ((row & 7) << 4);
}

// ---- pack W1/W2 (+ W3 padded to 32 cols) into 32x32x16 B-fragments ---------
// layers: elem = ((layer*8+kt)*4+tile)*512 + lane*8 + reg
//   B[k = kt*16 + (lane>>5)*8 + reg][n = tile*32 + (lane&31)]
// W3 (base 32768): elem = kt*512 + lane*8 + reg; n = lane&31 (<5 real)
__global__ void pack_w_kernel(const float* __restrict__ W1,
                              const float* __restrict__ W2,
                              const float* __restrict__ W3,
                              unsigned short* __restrict__ wsB) {
    int t = blockIdx.x * 256 + threadIdx.x;        // 0..36863
    if (t < 32768) {
        int reg   = t & 7;
        int lane  = (t >> 3) & 63;
        int tile  = (t >> 9) & 3;
        int kt    = (t >> 11) & 7;
        int layer = (t >> 14) & 1;
        int k = kt * 16 + ((lane >> 5) & 1) * 8 + reg;
        int n = tile * 32 + (lane & 31);
        const float* W = layer ? W2 : W1;
        wsB[t] = f2bf(W[k * HID + n]);
    } else if (t < 36864) {
        int tt = t - 32768;
        int reg  = tt & 7;
        int lane = (tt >> 3) & 63;
        int kt   = (tt >> 9) & 7;
        int k = kt * 16 + ((lane >> 5) & 1) * 8 + reg;
        int n = lane & 31;
        wsB[t] = (n < 5) ? f2bf(W3[k * 5 + n]) : (unsigned short)0;
    }
}

__global__ __launch_bounds__(256, 4) void mlp_pde_kernel(
    const float* __restrict__ x,
    const float* __restrict__ W0, const float* __restrict__ b0,
    const float* __restrict__ b1, const float* __restrict__ b2,
    const float* __restrict__ b3,
    const unsigned short* __restrict__ wsB,
    float* __restrict__ out, int nb)
{
    constexpr int PD[10] = {0,0,0,0,1,1,1,2,2,3};
    constexpr int PE[10] = {0,1,2,3,1,2,3,2,3,3};
    constexpr int ROWMAP[15] = {0,1,5,2,6,3,7,8,12,9,13,10,14,11,15}; // v->row
    constexpr int RB[8] = {0,1,2,3,8,9,10,11};     // reg -> base row (hi=0)

    __shared__ float lds[4][2048];                 // 8192 B per wave
    const int wave = threadIdx.x >> 6;
    const int lane = threadIdx.x & 63;
    float* wbase = lds[wave];
    char* abufA = (char*)wbase;                    // [16][128] bf16, swizzled
    char* abufB = (char*)wbase + 4096;
    float* combA = wbase;                          // overlap (dead after tfrag)
    float* combB = wbase + 82;
    int bA = blockIdx.x * 8 + wave * 2;
    int bB = bA + 1;
    if (bA >= nb) bA = nb - 1;
    if (bB >= nb) bB = nb - 1;

    // ---------------- layer 0 (4 -> 128), fp32, lane owns cols 2l,2l+1 ------
    {
        const int j0 = lane * 2;
        float w0d[4][2];
        #pragma unroll
        for (int d = 0; d < 4; ++d) {
            float2 w = *reinterpret_cast<const float2*>(W0 + d * HID + j0);
            w0d[d][0] = w.x; w0d[d][1] = w.y;
        }
        const float2 bb0 = *reinterpret_cast<const float2*>(b0 + j0);
        const float4 xvA = *reinterpret_cast<const float4*>(x + 4 * bA);
        const float4 xvB = *reinterpret_cast<const float4*>(x + 4 * bB);
        #pragma unroll
        for (int s = 0; s < 2; ++s) {
            const float4 xv = s ? xvB : xvA;
            char* abuf = s ? abufB : abufA;
            float val[15][2];
            #pragma unroll
            for (int jj = 0; jj < 2; ++jj) {
                float z = ((jj == 0) ? bb0.x : bb0.y)
                        + xv.x * w0d[0][jj] + xv.y * w0d[1][jj]
                        + xv.z * w0d[2][jj] + xv.w * w0d[3][jj];
                float h = tanh_fast(z);
                float sd = 1.f - h * h;
                val[0][jj] = h;
                #pragma unroll
                for (int d = 0; d < 4; ++d) val[1 + d][jj] = sd * w0d[d][jj];
                #pragma unroll
                for (int p = 0; p < 10; ++p)
                    val[5 + p][jj] = -2.f * h * sd * w0d[PD[p]][jj] * w0d[PE[p]][jj];
            }
            #pragma unroll
            for (int v = 0; v < 15; ++v)
                *reinterpret_cast<u32a*>(abuf + swz(ROWMAP[v], j0 * 2)) =
                    pk_bf16(val[v][0], val[v][1]);
            *reinterpret_cast<u32a*>(abuf + swz(4, j0 * 2)) = 0u;   // pad row
        }
    }
    LDS_FENCE();   // layer-0 stores -> afrag reads

    // ---------------- layers 1,2 via 32x32x16 MFMA (stacked samples) --------
    const int col  = lane & 31;                    // output column in tile
    const int hi   = lane >> 5;                    // lane half
    const int arow = lane & 15;                    // A-row within sample
    char* abufM = (char*)wbase + ((lane >> 4) & 1) * 4096;  // m>=16 -> sample B

    #pragma unroll 1
    for (int layer = 0; layer < 2; ++layer) {
        // A fragments: lane holds A[m=lane&31][k = kt*16 + hi*8 + 0..7]
        bf16x8 af[8];
        #pragma unroll
        for (int kt = 0; kt < 8; ++kt)
            af[kt] = *reinterpret_cast<const bf16x8*>(
                abufM + swz(arow, kt * 32 + hi * 16));
        LDS_FENCE();   // afrag reads -> recomb stores (WAR)
        const float* bias = layer ? b2 : b1;
        float bv[4];
        #pragma unroll
        for (int t4 = 0; t4 < 4; ++t4) bv[t4] = bias[t4 * 32 + col];

        #pragma unroll
        for (int t4 = 0; t4 < 4; ++t4) {
            f32x16 acc = {0.f,0.f,0.f,0.f,0.f,0.f,0.f,0.f,
                          0.f,0.f,0.f,0.f,0.f,0.f,0.f,0.f};
            #pragma unroll
            for (int kt = 0; kt < 8; ++kt) {
                bf16x8 bfrag = *reinterpret_cast<const bf16x8*>(
                    wsB + ((size_t)(((layer * 8 + kt) * 4) + t4) * 512 + lane * 8));
                acc = __builtin_amdgcn_mfma_f32_32x32x16_bf16(af[kt], bfrag, acc, 0, 0, 0);
            }
            // broadcasts: z,u0..u3 per sample (rows 0,1,5,2,6 / 16,17,21,18,22)
            float zA  = __shfl(acc[0],  col,      64);
            float uA0 = __shfl(acc[1],  col,      64);
            float uA1 = __shfl(acc[1],  col + 32, 64);
            float uA2 = __shfl(acc[2],  col,      64);
            float uA3 = __shfl(acc[2],  col + 32, 64);
            float zB  = __shfl(acc[8],  col,      64);
            float uB0 = __shfl(acc[9],  col,      64);
            float uB1 = __shfl(acc[9],  col + 32, 64);
            float uB2 = __shfl(acc[10], col,      64);
            float uB3 = __shfl(acc[10], col + 32, 64);
            float hA = tanh_fast(zA + bv[t4]);
            float sA = 1.f - hA * hA;  float cA = -2.f * hA * sA;
            float hB = tanh_fast(zB + bv[t4]);
            float sB = 1.f - hB * hB;  float cB = -2.f * hB * sB;
            const bool H = (hi != 0);

            float nvA[8], nvB[8];
            nvA[0] = H ? 0.f : hA;                              // rows 0/4: v0|pad
            nvA[1] = sA * (H ? uA1 : uA0);                      // rows 1/5: v1|v2
            nvA[2] = sA * (H ? uA3 : uA2);                      // rows 2/6: v3|v4
            nvA[3] = fmaf(cA * uA0, H ? uA1 : uA0, sA * acc[3]);    // v5|v6
            nvA[4] = fmaf(cA * uA0, H ? uA3 : uA2, sA * acc[4]);    // v7|v8
            nvA[5] = fmaf(cA * uA1, H ? uA2 : uA1, sA * acc[5]);    // v9|v10
            nvA[6] = fmaf(cA * (H ? uA2 : uA1), H ? uA2 : uA3, sA * acc[6]); // v11|v12
            nvA[7] = fmaf(cA * (H ? uA3 : uA2), uA3, sA * acc[7]);  // v13|v14
            nvB[0] = H ? 0.f : hB;
            nvB[1] = sB * (H ? uB1 : uB0);
            nvB[2] = sB * (H ? uB3 : uB2);
            nvB[3] = fmaf(cB * uB0, H ? uB1 : uB0, sB * acc[11]);
            nvB[4] = fmaf(cB * uB0, H ? uB3 : uB2, sB * acc[12]);
            nvB[5] = fmaf(cB * uB1, H ? uB2 : uB1, sB * acc[13]);
            nvB[6] = fmaf(cB * (H ? uB2 : uB1), H ? uB2 : uB3, sB * acc[14]);
            nvB[7] = fmaf(cB * (H ? uB3 : uB2), uB3, sB * acc[15]);

            const int cb = (t4 * 32 + col) * 2;
            #pragma unroll
            for (int q = 0; q < 8; ++q) {
                int rowq = RB[q] + 4 * hi;
                *reinterpret_cast<u16a*>(abufA + swz(rowq, cb)) = bf1(nvA[q]);
                *reinterpret_cast<u16a*>(abufB + swz(rowq, cb)) = bf1(nvB[q]);
            }
        }
        LDS_FENCE();   // recomb stores -> next-layer / epilogue reads
    }

    // ---------------- epilogue: stacked T @ W3pad(128x32) via MFMA ----------
    bf16x8 tf[8];
    #pragma unroll
    for (int kt = 0; kt < 8; ++kt)
        tf[kt] = *reinterpret_cast<const bf16x8*>(
            abufM + swz(arow, kt * 32 + hi * 16));
    LDS_FENCE();   // tfrag reads -> comb stores (comb overlaps abufA)

    f32x16 fa = {0.f,0.f,0.f,0.f,0.f,0.f,0.f,0.f,
                 0.f,0.f,0.f,0.f,0.f,0.f,0.f,0.f};
    #pragma unroll
    for (int kt = 0; kt < 8; ++kt) {
        bf16x8 w3f = *reinterpret_cast<const bf16x8*>(
            wsB + 32768 + (size_t)(kt * 512 + lane * 8));
        fa = __builtin_amdgcn_mfma_f32_32x32x16_bf16(tf[kt], w3f, fa, 0, 0, 0);
    }

    if (col < 5) {
        float badd = (hi != 0) ? 0.f : b3[col];
        #pragma unroll
        for (int q = 0; q < 8; ++q) {
            int rowq = RB[q] + 4 * hi;
            float tA = fa[q];
            float tB = fa[q + 8];
            if (q == 0) { tA += badd; tB += badd; }
            combA[rowq * 5 + col] = tA;            // comb indexed by permuted row
            combB[rowq * 5 + col] = tB;
        }
    }
    if (lane == 63) { combA[80] = 0.f; combA[81] = 1.f; combB[80] = 0.f; combB[81] = 1.f; }
    LDS_FENCE();   // comb stores -> table reads

    // ---------------- table-driven writer: 38 outputs per sample ------------
    if (lane < 38) {
        OSpec sp = g_ospec[lane];
        float a1v = (combA[sp.a0] + combA[sp.a1] + combA[sp.a2]) * combA[sp.m] * sp.s1;
        float a2v = (combA[sp.b0] + combA[sp.b1] + combA[sp.b2]) * combA[sp.m2] * sp.s2;
        out[sp.base * nb + bA * sp.mul + sp.off] = a1v + a2v;
        float c1v = (combB[sp.a0] + combB[sp.a1] + combB[sp.a2]) * combB[sp.m] * sp.s1;
        float c2v = (combB[sp.b0] + combB[sp.b1] + combB[sp.b2]) * combB[sp.m2] * sp.s2;
        out[sp.base * nb + bB * sp.mul + sp.off] = c1v + c2v;
    }
}

} // namespace

extern "C" void kernel_launch(void* const* d_in, const int* in_sizes, int n_in,
                              void* d_out, int out_size, void* d_ws, size_t ws_size,
                              hipStream_t stream) {
    const float* x  = (const float*)d_in[0];
    const float* W0 = (const float*)d_in[1];
    const float* b0 = (const float*)d_in[2];
    const float* W1 = (const float*)d_in[3];
    const float* b1 = (const float*)d_in[4];
    const float* W2 = (const float*)d_in[5];
    const float* b2 = (const float*)d_in[6];
    const float* W3 = (const float*)d_in[7];
    const float* b3 = (const float*)d_in[8];
    float* out = (float*)d_out;
    unsigned short* wsB = (unsigned short*)d_ws;   // ~72 KB used

    const int nb = in_sizes[0] / 4;                // 32768
    pack_w_kernel<<<144, 256, 0, stream>>>(W1, W2, W3, wsB);
    const int blocks = (nb + 7) / 8;               // 8 samples (4 waves x 2) per block
    mlp_pde_kernel<<<blocks, 256, 0, stream>>>(x, W0, b0, b1, b2, b3, wsB, out, nb);
}